// Round 2
// baseline (63.954 us; speedup 1.0000x reference)
//
#include <hip/hip_runtime.h>
#include <hip/hip_bf16.h>

#define NB 8
#define NS 256
#define NN 128
#define NC 64
#define NH 4
#define AH 128
#define HID 256
#define FH 32

// ws float layout:
// [0, 1024)      E[b][n] = exp(bias[b][n])
// [1024, 1536)   T[b][c] = sum of E over members of cluster c (0 if empty)
// [1536, 1792)   const0[o] = ffn_b[o] + sum_k ffn_w[o][k]*val_b[k]
// [1792, 2816)   W[o][h]  = sum_d ffn_w[o][h*32+d]*val_w[h*32+d]
// [2816, 2820)   ew[h] = exp(attn_w[h])

__global__ __launch_bounds__(1024) void prep_kernel(
    const int* __restrict__ labels,
    const float* __restrict__ sp_d, const float* __restrict__ tp_d,
    const float* __restrict__ c_sp_p, const float* __restrict__ sp_w1, const float* __restrict__ sp_w2,
    const float* __restrict__ c_tp_p, const float* __restrict__ tp_w1, const float* __restrict__ tp_w2,
    const float* __restrict__ attn_w,
    const float* __restrict__ val_w, const float* __restrict__ val_b,
    const float* __restrict__ ffn_w, const float* __restrict__ ffn_b,
    float* __restrict__ ws)
{
    __shared__ float sE[NB * NN];
    const int t = threadIdx.x;  // 0..1023 == (b,n)

    // --- FIRE bias -> E[b][n] ---
    {
        const float csp = fmaxf(c_sp_p[0], 0.0f);
        const float ctp = fmaxf(c_tp_p[0], 0.0f);
        const float dsp = sp_d[t];
        const float dtp = tp_d[t];
        const float dns = __logf(fmaf(csp, dsp, 1.0f)) / __logf(fmaf(csp, 180.0f, 1.0f));
        const float dnt = __logf(fmaf(ctp, dtp, 1.0f)) / __logf(fmaf(ctp, 365.0f, 1.0f));
        float bias_sp = 0.f, bias_tp = 0.f;
        for (int j = 0; j < FH; ++j) {
            const float zs = dns * sp_w1[j];
            bias_sp += (zs / (1.0f + __expf(-zs))) * sp_w2[j];
            const float zt = dnt * tp_w1[j];
            bias_tp += (zt / (1.0f + __expf(-zt))) * tp_w2[j];
        }
        const float e = __expf(bias_sp + bias_tp);
        sE[t] = e;
        ws[t] = e;
    }
    __syncthreads();

    // --- T[b][c] (deterministic scan, no atomics) ---
    if (t < NB * NC) {
        const int b = t >> 6, c = t & (NC - 1);
        const int* lab = labels + b * NN;
        const float* eb = sE + b * NN;
        float sum = 0.f;
        for (int n = 0; n < NN; ++n)
            sum += (lab[n] == c) ? eb[n] : 0.f;
        ws[1024 + t] = sum;
    }

    // --- const0[o], W[o][h] ---
    if (t < HID) {
        const float* fr = ffn_w + t * AH;
        float c0 = ffn_b[t];
        float w[NH];
        #pragma unroll
        for (int h = 0; h < NH; ++h) {
            float wh = 0.f;
            for (int d = 0; d < 32; ++d) {
                const float f = fr[h * 32 + d];
                c0 = fmaf(f, val_b[h * 32 + d], c0);
                wh = fmaf(f, val_w[h * 32 + d], wh);
            }
            w[h] = wh;
        }
        ws[1536 + t] = c0;
        #pragma unroll
        for (int h = 0; h < NH; ++h) ws[1792 + t * NH + h] = w[h];
    }
    if (t < NH) ws[2816 + t] = __expf(attn_w[t]);
}

__global__ __launch_bounds__(256) void out_kernel(
    const int* __restrict__ src,      // (B,S,N) int32, values {0,1}
    const int* __restrict__ labels,   // (B,N)
    const float* __restrict__ ws,
    float* __restrict__ out)          // (B,S,C,HID) float32
{
    __shared__ float sE[NN];
    __shared__ int   sLab[NN];
    __shared__ int   sX[NN];
    __shared__ float sBs[NC];
    __shared__ float sP1[NC][NH];
    __shared__ float sHm[NC];

    const int blk = blockIdx.x;      // b*NS + s
    const int b = blk >> 8;          // NS == 256
    const int t = threadIdx.x;

    if (t < NN) {
        sE[t]   = ws[b * NN + t];
        sLab[t] = labels[b * NN + t];
        sX[t]   = src[(size_t)blk * NN + t];
    }
    __syncthreads();

    // Bs[c] = sum of E over members of c with x==1 (deterministic scan)
    if (t < NC) {
        float bs = 0.f;
        for (int n = 0; n < NN; ++n)
            bs += (sLab[n] == t && sX[n] != 0) ? sE[n] : 0.f;
        sBs[t] = bs;
    }
    __syncthreads();

    // P1[c][h] and member mask
    if (t < NC * NH) {
        const int c = t >> 2, h = t & 3;
        const float T  = ws[1024 + b * NC + c];
        const float bs = sBs[c];
        const float ew = ws[2816 + h];
        float p1 = 0.f, hm = 0.f;
        if (T > 0.f) {
            hm = 1.f;
            p1 = (bs * ew) / ((T - bs) + bs * ew);
        }
        sP1[c][h] = p1;
        if (h == 0) sHm[c] = hm;
    }
    __syncthreads();

    // Output: each thread owns 4 consecutive o (one float4), iterates 16 clusters.
    const int o0 = (t & 63) * 4;     // 0..255, step 4
    const int crow = t >> 6;         // 0..3
    float c0[4], w0[4], w1[4], w2[4], w3[4];
    #pragma unroll
    for (int i = 0; i < 4; ++i) {
        c0[i] = ws[1536 + o0 + i];
        const float* wp = ws + 1792 + (size_t)(o0 + i) * NH;
        w0[i] = wp[0]; w1[i] = wp[1]; w2[i] = wp[2]; w3[i] = wp[3];
    }
    float* orow = out + (size_t)blk * (NC * HID);
    #pragma unroll
    for (int ci = 0; ci < 16; ++ci) {
        const int c = ci * 4 + crow;
        const float p0 = sP1[c][0], p1v = sP1[c][1], p2 = sP1[c][2], p3 = sP1[c][3];
        const float hm = sHm[c];
        float4 val;
        float* vp = &val.x;
        #pragma unroll
        for (int i = 0; i < 4; ++i) {
            float v = c0[i];
            v = fmaf(p0,  w0[i], v);
            v = fmaf(p1v, w1[i], v);
            v = fmaf(p2,  w2[i], v);
            v = fmaf(p3,  w3[i], v);
            vp[i] = v * hm;
        }
        *reinterpret_cast<float4*>(orow + (size_t)c * HID + o0) = val;
    }
}

extern "C" void kernel_launch(void* const* d_in, const int* in_sizes, int n_in,
                              void* d_out, int out_size, void* d_ws, size_t ws_size,
                              hipStream_t stream) {
    const int*   src    = (const int*)d_in[0];
    const int*   labels = (const int*)d_in[1];
    const float* sp_d   = (const float*)d_in[2];
    const float* tp_d   = (const float*)d_in[3];
    // d_in[4] = num_clusters (fixed 64)
    const float* c_sp   = (const float*)d_in[5];
    const float* sp_w1  = (const float*)d_in[6];
    const float* sp_w2  = (const float*)d_in[7];
    const float* c_tp   = (const float*)d_in[8];
    const float* tp_w1  = (const float*)d_in[9];
    const float* tp_w2  = (const float*)d_in[10];
    const float* attn_w = (const float*)d_in[11];
    // d_in[12] = attn_b: cancels in softmax over n — unused
    const float* val_w  = (const float*)d_in[13];
    const float* val_b  = (const float*)d_in[14];
    const float* ffn_w  = (const float*)d_in[15];
    const float* ffn_b  = (const float*)d_in[16];
    float* ws = (float*)d_ws;
    float* out = (float*)d_out;

    prep_kernel<<<1, 1024, 0, stream>>>(labels, sp_d, tp_d, c_sp, sp_w1, sp_w2,
                                        c_tp, tp_w1, tp_w2, attn_w, val_w, val_b,
                                        ffn_w, ffn_b, ws);
    out_kernel<<<NB * NS, 256, 0, stream>>>(src, labels, ws, out);
}

// Round 4
// 38.954 us; speedup vs baseline: 1.6418x; 1.6418x over previous
//
#include <hip/hip_runtime.h>
#include <hip/hip_bf16.h>

#define NB 8
#define NS 256
#define NN 128
#define NC 64
#define NH 4
#define AH 128
#define HID 256
#define FH 32

typedef float f32x4 __attribute__((ext_vector_type(4)));

// ws float layout:
// [0, 1024)      E[b][n] = exp(bias[b][n])
// [1024, 1536)   T[b][c] = sum of E over members of cluster c (0 if empty)
// [1536, 1792)   const0[o] = ffn_b[o] + sum_k ffn_w[o][k]*val_b[k]
// [1792, 2816)   W[o][h]  = sum_d ffn_w[o][h*32+d]*val_w[h*32+d]
// [2816, 2820)   ew[h] = exp(attn_w[h])

__global__ __launch_bounds__(256) void prep_kernel(
    const int* __restrict__ labels,
    const float* __restrict__ sp_d, const float* __restrict__ tp_d,
    const float* __restrict__ c_sp_p, const float* __restrict__ sp_w1, const float* __restrict__ sp_w2,
    const float* __restrict__ c_tp_p, const float* __restrict__ tp_w1, const float* __restrict__ tp_w2,
    const float* __restrict__ attn_w,
    const float* __restrict__ val_w, const float* __restrict__ val_b,
    const float* __restrict__ ffn_w, const float* __restrict__ ffn_b,
    float* __restrict__ ws)
{
    const int blk = blockIdx.x;
    const int t = threadIdx.x;

    if (blk < NB) {
        // ---- per-batch: FIRE bias -> E[b][n], then T[b][c] ----
        const int b = blk;
        __shared__ float sE[NN];
        __shared__ int   sLab[NN];
        __shared__ float sW1s[FH], sW2s[FH], sW1t[FH], sW2t[FH];

        if (t < FH) {
            sW1s[t] = sp_w1[t]; sW2s[t] = sp_w2[t];
            sW1t[t] = tp_w1[t]; sW2t[t] = tp_w2[t];
        }
        __syncthreads();

        if (t < NN) {
            const float csp = fmaxf(c_sp_p[0], 0.0f);
            const float ctp = fmaxf(c_tp_p[0], 0.0f);
            const float dsp = sp_d[b * NN + t];
            const float dtp = tp_d[b * NN + t];
            const float dns = __logf(fmaf(csp, dsp, 1.0f)) / __logf(fmaf(csp, 180.0f, 1.0f));
            const float dnt = __logf(fmaf(ctp, dtp, 1.0f)) / __logf(fmaf(ctp, 365.0f, 1.0f));
            float bias_sp = 0.f, bias_tp = 0.f;
            #pragma unroll
            for (int j = 0; j < FH; ++j) {
                const float zs = dns * sW1s[j];
                bias_sp += (zs / (1.0f + __expf(-zs))) * sW2s[j];
                const float zt = dnt * sW1t[j];
                bias_tp += (zt / (1.0f + __expf(-zt))) * sW2t[j];
            }
            const float e = __expf(bias_sp + bias_tp);
            sE[t] = e;
            sLab[t] = labels[b * NN + t];
            ws[b * NN + t] = e;
        }
        __syncthreads();

        // T[b][c]: 4 threads per cluster, interleaved n = 4i|q (LDS broadcast)
        {
            const int c = t >> 2, q = t & 3;
            float sum = 0.f;
            #pragma unroll
            for (int i = 0; i < 32; ++i) {
                const int n = (i << 2) | q;
                sum += (sLab[n] == c) ? sE[n] : 0.f;
            }
            sum += __shfl_xor(sum, 1);
            sum += __shfl_xor(sum, 2);
            if (q == 0) ws[1024 + b * NC + c] = sum;
        }
    } else {
        // ---- ffn fold: const0[o], W[o][h], ew[h] ----
        __shared__ float sVw[AH], sVb[AH];
        if (t < AH) { sVw[t] = val_w[t]; sVb[t] = val_b[t]; }
        __syncthreads();

        const int o = t;  // 0..255
        const float4* fr = reinterpret_cast<const float4*>(ffn_w + o * AH);
        float c0 = ffn_b[o];
        float w[NH] = {0.f, 0.f, 0.f, 0.f};
        #pragma unroll
        for (int k4 = 0; k4 < AH / 4; ++k4) {
            const float4 f = fr[k4];
            const int k = k4 * 4;
            const int h = k >> 5;
            c0 = fmaf(f.x, sVb[k], fmaf(f.y, sVb[k + 1], fmaf(f.z, sVb[k + 2], fmaf(f.w, sVb[k + 3], c0))));
            w[h] = fmaf(f.x, sVw[k], fmaf(f.y, sVw[k + 1], fmaf(f.z, sVw[k + 2], fmaf(f.w, sVw[k + 3], w[h]))));
        }
        ws[1536 + o] = c0;
        float4 wv = make_float4(w[0], w[1], w[2], w[3]);
        *reinterpret_cast<float4*>(ws + 1792 + o * NH) = wv;
        if (t < NH) ws[2816 + t] = __expf(attn_w[t]);
    }
}

__global__ __launch_bounds__(256) void out_kernel(
    const int* __restrict__ src,      // (B,S,N) int32, values {0,1}
    const int* __restrict__ labels,   // (B,N)
    const float* __restrict__ ws,
    float* __restrict__ out)          // (B,S,C,HID) float32
{
    __shared__ float sEx[NN];
    __shared__ int   sLab[NN];
    __shared__ float sP1[NC][NH];
    __shared__ float sHm[NC];

    const int blk = blockIdx.x;      // b*NS + s
    const int b = blk >> 8;          // NS == 256
    const int t = threadIdx.x;

    if (t < NN) {
        const float e = ws[b * NN + t];
        const int   x = src[(size_t)blk * NN + t];
        sLab[t] = labels[b * NN + t];
        sEx[t]  = x ? e : 0.f;
    }
    __syncthreads();

    // Bs + P1: 4 threads per cluster, thread q also computes head h=q.
    {
        const int c = t >> 2, q = t & 3;
        float bs = 0.f;
        #pragma unroll
        for (int i = 0; i < 32; ++i) {
            const int n = (i << 2) | q;
            bs += (sLab[n] == c) ? sEx[n] : 0.f;
        }
        bs += __shfl_xor(bs, 1);
        bs += __shfl_xor(bs, 2);
        const float T = ws[1024 + b * NC + c];
        float p1 = 0.f, hm = 0.f;
        if (T > 0.f) {
            hm = 1.f;
            const float ew = ws[2816 + q];
            p1 = (bs * ew) / ((T - bs) + bs * ew);
        }
        sP1[c][q] = p1;
        if (q == 0) sHm[c] = hm;
    }
    __syncthreads();

    // Output: thread owns 4 consecutive o (one float4), iterates 16 clusters.
    const int o0 = (t & 63) * 4;     // 0..255, step 4
    const int crow = t >> 6;         // 0..3
    float c0[4], w0[4], w1[4], w2[4], w3[4];
    #pragma unroll
    for (int i = 0; i < 4; ++i) {
        c0[i] = ws[1536 + o0 + i];
        const float* wp = ws + 1792 + (size_t)(o0 + i) * NH;
        w0[i] = wp[0]; w1[i] = wp[1]; w2[i] = wp[2]; w3[i] = wp[3];
    }
    float* orow = out + (size_t)blk * (NC * HID);
    #pragma unroll
    for (int ci = 0; ci < 16; ++ci) {
        const int c = ci * 4 + crow;
        const float p0 = sP1[c][0], p1v = sP1[c][1], p2 = sP1[c][2], p3 = sP1[c][3];
        const float hm = sHm[c];
        f32x4 val;
        #pragma unroll
        for (int i = 0; i < 4; ++i) {
            float v = c0[i];
            v = fmaf(p0,  w0[i], v);
            v = fmaf(p1v, w1[i], v);
            v = fmaf(p2,  w2[i], v);
            val[i] = fmaf(p3, w3[i], v) * hm;
        }
        __builtin_nontemporal_store(val, reinterpret_cast<f32x4*>(orow + (size_t)c * HID + o0));
    }
}

extern "C" void kernel_launch(void* const* d_in, const int* in_sizes, int n_in,
                              void* d_out, int out_size, void* d_ws, size_t ws_size,
                              hipStream_t stream) {
    const int*   src    = (const int*)d_in[0];
    const int*   labels = (const int*)d_in[1];
    const float* sp_d   = (const float*)d_in[2];
    const float* tp_d   = (const float*)d_in[3];
    // d_in[4] = num_clusters (fixed 64)
    const float* c_sp   = (const float*)d_in[5];
    const float* sp_w1  = (const float*)d_in[6];
    const float* sp_w2  = (const float*)d_in[7];
    const float* c_tp   = (const float*)d_in[8];
    const float* tp_w1  = (const float*)d_in[9];
    const float* tp_w2  = (const float*)d_in[10];
    const float* attn_w = (const float*)d_in[11];
    // d_in[12] = attn_b: cancels in softmax over n — unused
    const float* val_w  = (const float*)d_in[13];
    const float* val_b  = (const float*)d_in[14];
    const float* ffn_w  = (const float*)d_in[15];
    const float* ffn_b  = (const float*)d_in[16];
    float* ws = (float*)d_ws;
    float* out = (float*)d_out;

    prep_kernel<<<NB + 1, 256, 0, stream>>>(labels, sp_d, tp_d, c_sp, sp_w1, sp_w2,
                                            c_tp, tp_w1, tp_w2, attn_w, val_w, val_b,
                                            ffn_w, ffn_b, ws);
    out_kernel<<<NB * NS, 256, 0, stream>>>(src, labels, ws, out);
}